// Round 7
// baseline (655.831 us; speedup 1.0000x reference)
//
#include <hip/hip_runtime.h>
#include <stdint.h>

// ---------------------------------------------------------------------------
// MHA forward. Inputs fp32, output fp32. Internal bf16 MFMA.
//   B=4, S=2048, D=1024, H=16, hd=64.
// converts -> gemm_qkv (x@W^T+b; q pre-scaled by 0.125*log2e; v stored as
// V^T [BH,hd,S]) -> flash attn (fixed-max softmax, ZERO barriers: K and V
// frags straight from global, P wave-private in LDS) -> convert Wo ->
// gemm_o (fp32 store) -> d_out.
// ws (64 MB): xb|ao [0,NT) q [NT,2NT) k [2NT,3NT) vt [3NT,4NT).
// d_out doubles as bf16 scratch for Wq/Wk/Wv before gemm_o overwrites it.
// ---------------------------------------------------------------------------

typedef __attribute__((ext_vector_type(8))) short bfx8;   // 8 bf16 (4 VGPRs)
typedef __attribute__((ext_vector_type(4))) float fx4;    // MFMA C/D

#define MFMA_16x16x32(A, B, C) __builtin_amdgcn_mfma_f32_16x16x32_bf16(A, B, C, 0, 0, 0)

__device__ __forceinline__ unsigned short f2bf(float f) {
  union { float f; uint32_t u; } v; v.f = f;
  uint32_t r = v.u + 0x7fffu + ((v.u >> 16) & 1u);  // RNE
  return (unsigned short)(r >> 16);
}
__device__ __forceinline__ unsigned short f2bf_fast(float f) {  // round-half-up (p>=0)
  union { float f; uint32_t u; } v; v.f = f;
  return (unsigned short)((v.u + 0x8000u) >> 16);
}
__device__ __forceinline__ void async16(unsigned short* l, const unsigned short* g) {
  // global -> LDS direct copy, 16B/lane. Effective LDS dest = wave base + lane*16.
  __builtin_amdgcn_global_load_lds((const __attribute__((address_space(1))) void*)g,
                                   (__attribute__((address_space(3))) void*)l,
                                   16, 0, 0);
}

// ---------------------------------------------------------------------------
// fp32 -> bf16 converts
// ---------------------------------------------------------------------------
__global__ __launch_bounds__(256) void convert_f32_bf16(
    const float* __restrict__ src, unsigned short* __restrict__ dst, int n4) {
  const int i = blockIdx.x * 256 + threadIdx.x;
  if (i >= n4) return;
  const float4 v = ((const float4*)src)[i];
  ushort4 o;
  o.x = f2bf(v.x); o.y = f2bf(v.y); o.z = f2bf(v.z); o.w = f2bf(v.w);
  ((ushort4*)dst)[i] = o;
}

__global__ __launch_bounds__(256) void convert3_f32_bf16(
    const float* __restrict__ s0, const float* __restrict__ s1,
    const float* __restrict__ s2,
    unsigned short* __restrict__ d0, unsigned short* __restrict__ d1,
    unsigned short* __restrict__ d2, int n4) {
  const int which = blockIdx.y;
  const float* src = (which == 0) ? s0 : ((which == 1) ? s1 : s2);
  unsigned short* dst = (which == 0) ? d0 : ((which == 1) ? d1 : d2);
  const int i = blockIdx.x * 256 + threadIdx.x;
  if (i >= n4) return;
  const float4 v = ((const float4*)src)[i];
  ushort4 o;
  o.x = f2bf(v.x); o.y = f2bf(v.y); o.z = f2bf(v.z); o.w = f2bf(v.w);
  ((ushort4*)dst)[i] = o;
}

// ---------------------------------------------------------------------------
// GEMM: Y = X @ W^T + b.  128x128 tile, BK=32, 4 waves 2x2, 4x4 16x16 subtiles.
// which==0 (q): out *= 0.125*log2e. which==2 (v): stores V^T [BH, hd, S].
// ---------------------------------------------------------------------------

__global__ __launch_bounds__(256) void gemm_qkv(
    const unsigned short* __restrict__ X,
    const unsigned short* __restrict__ Wq, const unsigned short* __restrict__ Wk,
    const unsigned short* __restrict__ Wv,
    const float* __restrict__ bq, const float* __restrict__ bk,
    const float* __restrict__ bv,
    unsigned short* __restrict__ outq, unsigned short* __restrict__ outk,
    unsigned short* __restrict__ outv) {
  __shared__ unsigned short ldsA[128 * 32];
  __shared__ unsigned short ldsB[128 * 32];
  const int tid = threadIdx.x;
  const int w = tid >> 6, lane = tid & 63, quad = lane >> 4, l15 = lane & 15;
  const int m0 = blockIdx.x * 128;
  const int which = blockIdx.y >> 3;          // 0:q 1:k 2:v
  const int n0 = (blockIdx.y & 7) * 128;
  const unsigned short* W = (which == 0) ? Wq : ((which == 1) ? Wk : Wv);
  const float* bias       = (which == 0) ? bq : ((which == 1) ? bk : bv);
  unsigned short* Y       = (which == 0) ? outq : ((which == 1) ? outk : outv);
  const int wm = (w >> 1) * 64, wn = (w & 1) * 64;
  const int srow = tid >> 2, scol = (tid & 3) * 8;   // per-lane 16B staging
  fx4 acc[4][4] = {};
  for (int k0 = 0; k0 < 1024; k0 += 32) {
    __syncthreads();
    async16(&ldsA[srow * 32 + scol],        X + (size_t)(m0 + srow) * 1024 + k0 + scol);
    async16(&ldsA[(srow + 64) * 32 + scol], X + (size_t)(m0 + srow + 64) * 1024 + k0 + scol);
    async16(&ldsB[srow * 32 + scol],        W + (size_t)(n0 + srow) * 1024 + k0 + scol);
    async16(&ldsB[(srow + 64) * 32 + scol], W + (size_t)(n0 + srow + 64) * 1024 + k0 + scol);
    __syncthreads();
    bfx8 af[4], bfr[4];
#pragma unroll
    for (int i = 0; i < 4; i++) af[i]  = *(const bfx8*)&ldsA[(wm + i * 16 + l15) * 32 + quad * 8];
#pragma unroll
    for (int j = 0; j < 4; j++) bfr[j] = *(const bfx8*)&ldsB[(wn + j * 16 + l15) * 32 + quad * 8];
#pragma unroll
    for (int i = 0; i < 4; i++)
#pragma unroll
      for (int j = 0; j < 4; j++)
        acc[i][j] = MFMA_16x16x32(af[i], bfr[j], acc[i][j]);
  }
  const float qscale = 0.18033688011112042f;  // 0.125 * log2(e)
  float bv_[4];
#pragma unroll
  for (int j = 0; j < 4; j++) bv_[j] = bias[n0 + wn + j * 16 + l15];
#pragma unroll
  for (int i = 0; i < 4; i++) {
#pragma unroll
    for (int r = 0; r < 4; r++) {
      const int m_g = m0 + wm + i * 16 + quad * 4 + r;     // C/D: row = quad*4+reg
      const int bb = m_g >> 11, ss = m_g & 2047;
#pragma unroll
      for (int j = 0; j < 4; j++) {
        const int n_g = n0 + wn + j * 16 + l15;            // C/D: col = lane&15
        const int h = n_g >> 6, d = n_g & 63;
        float o = acc[i][j][r] + bv_[j];
        if (which == 0) o *= qscale;                       // wave-uniform branch
        if (which == 2)  // V^T: [BH, hd, S]
          Y[((size_t)(bb * 16 + h) * 64 + d) * 2048 + ss] = f2bf(o);
        else
          Y[(((size_t)(bb * 16 + h)) * 2048 + ss) * 64 + d] = f2bf(o);
      }
    }
  }
}

__global__ __launch_bounds__(256) void gemm_o(
    const unsigned short* __restrict__ X,   // attn_out [8192,1024] bf16
    const unsigned short* __restrict__ W,   // Wo bf16
    const float* __restrict__ bias,
    float* __restrict__ Y) {                // d_out [8192,1024] fp32
  __shared__ unsigned short ldsA[128 * 32];
  __shared__ unsigned short ldsB[128 * 32];
  const int tid = threadIdx.x;
  const int w = tid >> 6, lane = tid & 63, quad = lane >> 4, l15 = lane & 15;
  const int m0 = blockIdx.x * 128;
  const int n0 = blockIdx.y * 128;
  const int wm = (w >> 1) * 64, wn = (w & 1) * 64;
  const int srow = tid >> 2, scol = (tid & 3) * 8;
  fx4 acc[4][4] = {};
  for (int k0 = 0; k0 < 1024; k0 += 32) {
    __syncthreads();
    async16(&ldsA[srow * 32 + scol],        X + (size_t)(m0 + srow) * 1024 + k0 + scol);
    async16(&ldsA[(srow + 64) * 32 + scol], X + (size_t)(m0 + srow + 64) * 1024 + k0 + scol);
    async16(&ldsB[srow * 32 + scol],        W + (size_t)(n0 + srow) * 1024 + k0 + scol);
    async16(&ldsB[(srow + 64) * 32 + scol], W + (size_t)(n0 + srow + 64) * 1024 + k0 + scol);
    __syncthreads();
    bfx8 af[4], bfr[4];
#pragma unroll
    for (int i = 0; i < 4; i++) af[i]  = *(const bfx8*)&ldsA[(wm + i * 16 + l15) * 32 + quad * 8];
#pragma unroll
    for (int j = 0; j < 4; j++) bfr[j] = *(const bfx8*)&ldsB[(wn + j * 16 + l15) * 32 + quad * 8];
#pragma unroll
    for (int i = 0; i < 4; i++)
#pragma unroll
      for (int j = 0; j < 4; j++)
        acc[i][j] = MFMA_16x16x32(af[i], bfr[j], acc[i][j]);
  }
  float bv_[4];
#pragma unroll
  for (int j = 0; j < 4; j++) bv_[j] = bias[n0 + wn + j * 16 + l15];
#pragma unroll
  for (int i = 0; i < 4; i++) {
#pragma unroll
    for (int r = 0; r < 4; r++) {
      const int m_g = m0 + wm + i * 16 + quad * 4 + r;
#pragma unroll
      for (int j = 0; j < 4; j++) {
        const int n_g = n0 + wn + j * 16 + l15;
        Y[(size_t)m_g * 1024 + n_g] = acc[i][j][r] + bv_[j];
      }
    }
  }
}

// ---------------------------------------------------------------------------
// Flash attention, fixed-max softmax (q pre-scaled by 0.125*log2e).
// Q,K: [BH,S,64]; VT: [BH,64,S]. Block = (b,h) x 64 q rows; 4 waves x 16 q.
// ZERO barriers, P-LDS only (8.7 KB):
//   - K frags AND V frags (B-layout B[n=d][k=kv], 8 contiguous kv from the
//     VT layout) are loaded straight from global (L2-resident, 512 KB/head
//     shared by 32 blocks). No cross-wave LDS structure exists.
//   - P round-trips wave-private LDS; write->read ordering is intra-wave
//     lgkmcnt, enforced explicitly with s_waitcnt lgkmcnt(0).
// ---------------------------------------------------------------------------

#define P_LD 68

__global__ __launch_bounds__(256) void attn_kernel(
    const unsigned short* __restrict__ Q, const unsigned short* __restrict__ K,
    const unsigned short* __restrict__ VT, unsigned short* __restrict__ O) {
  __shared__ unsigned short lds_p[4][16 * P_LD];   // per-wave P (8.7 KB total)
  const int tid = threadIdx.x;
  const int w = tid >> 6, lane = tid & 63, quad = lane >> 4, l15 = lane & 15;
  const int bh = blockIdx.y;
  const size_t hoff = (size_t)bh * 2048 * 64;
  const unsigned short* Qh = Q + hoff;
  const int q0 = blockIdx.x * 64 + w * 16;

  // Q fragments (A-layout: m=lane&15, k=quad*8+j), pre-scaled, live all loop
  bfx8 qf0 = *(const bfx8*)&Qh[(size_t)(q0 + l15) * 64 + quad * 8];
  bfx8 qf1 = *(const bfx8*)&Qh[(size_t)(q0 + l15) * 64 + 32 + quad * 8];

  fx4 o_acc[4] = {};
  float l_r[4] = {0.f, 0.f, 0.f, 0.f};

  // Per-tile walking pointers (lane-dependent base folded in once).
  // K frag (nj, half): Kt + nj*16*64 + half*32   [row = kv, K-contig]
  // V frag (nj, half): Vt + nj*16*2048 + half*32 [row = d, kv-contig]
  const unsigned short* Kt = K + hoff + (size_t)l15 * 64 + quad * 8;
  const unsigned short* Vt = VT + hoff + (size_t)l15 * 2048 + quad * 8;

  for (int t = 0; t < 32; ++t) {
    // ---- S = Q K^T (16 x 64 per wave), K frags from global
    fx4 s_acc[4];
#pragma unroll
    for (int nj = 0; nj < 4; nj++) {
      bfx8 kf0 = *(const bfx8*)(Kt + (size_t)nj * 1024);
      bfx8 kf1 = *(const bfx8*)(Kt + (size_t)nj * 1024 + 32);
      fx4 z = {};
      z = MFMA_16x16x32(qf0, kf0, z);
      z = MFMA_16x16x32(qf1, kf1, z);
      s_acc[nj] = z;
    }

    // ---- V frags for this tile (independent of softmax; latency hidden)
    bfx8 vf0[4], vf1[4];
#pragma unroll
    for (int nj = 0; nj < 4; nj++) {
      vf0[nj] = *(const bfx8*)(Vt + (size_t)nj * 16 * 2048);
      vf1[nj] = *(const bfx8*)(Vt + (size_t)nj * 16 * 2048 + 32);
    }

    // ---- fixed-max softmax: p = exp2(z); per-lane l partials; P -> LDS bf16
#pragma unroll
    for (int r = 0; r < 4; r++) {
      float p0 = exp2f(s_acc[0][r]);
      float p1 = exp2f(s_acc[1][r]);
      float p2 = exp2f(s_acc[2][r]);
      float p3 = exp2f(s_acc[3][r]);
      l_r[r] += (p0 + p1) + (p2 + p3);
      const int pbase = (quad * 4 + r) * P_LD + l15;
      lds_p[w][pbase]      = f2bf_fast(p0);
      lds_p[w][pbase + 16] = f2bf_fast(p1);
      lds_p[w][pbase + 32] = f2bf_fast(p2);
      lds_p[w][pbase + 48] = f2bf_fast(p3);
    }

    // wave-private LDS: enforce write->read ordering within this wave only
    __asm__ volatile("s_waitcnt lgkmcnt(0)" ::: "memory");

    // ---- O += P V   (P A-layout from LDS; V B-frags already in regs)
    bfx8 pf0 = *(const bfx8*)&lds_p[w][l15 * P_LD + quad * 8];
    bfx8 pf1 = *(const bfx8*)&lds_p[w][l15 * P_LD + 32 + quad * 8];
#pragma unroll
    for (int nj = 0; nj < 4; nj++) {
      o_acc[nj] = MFMA_16x16x32(pf0, vf0[nj], o_acc[nj]);
      o_acc[nj] = MFMA_16x16x32(pf1, vf1[nj], o_acc[nj]);
    }

    Kt += 64 * 64;   // next 64 kv rows
    Vt += 64;        // next 64 kv cols
  }

  // epilogue: reduce l across the 16 lanes holding each row, O /= l, store
  const int bb = bh >> 4, h = bh & 15;
#pragma unroll
  for (int r = 0; r < 4; r++) {
    float s = l_r[r];
#pragma unroll
    for (int d = 1; d < 16; d <<= 1) s += __shfl_xor(s, d, 64);
    const float inv = 1.0f / s;
    const int qrow = q0 + quad * 4 + r;
    const size_t base = ((size_t)(bb * 2048 + qrow)) * 1024 + h * 64;
#pragma unroll
    for (int nj = 0; nj < 4; nj++)
      O[base + nj * 16 + l15] = f2bf(o_acc[nj][r] * inv);
  }
}

// ---------------------------------------------------------------------------

extern "C" void kernel_launch(void* const* d_in, const int* in_sizes, int n_in,
                              void* d_out, int out_size, void* d_ws, size_t ws_size,
                              hipStream_t stream) {
  const float* x = (const float*)d_in[0];
  const float *Wq, *Wk, *Wv, *Wo, *bq, *bk, *bv, *bo;
  if (in_sizes[2] == 1024) {  // setup_inputs() dict order: x,Wq,bq,Wk,bk,Wv,bv,Wo,bo
    Wq = (const float*)d_in[1]; bq = (const float*)d_in[2];
    Wk = (const float*)d_in[3]; bk = (const float*)d_in[4];
    Wv = (const float*)d_in[5]; bv = (const float*)d_in[6];
    Wo = (const float*)d_in[7]; bo = (const float*)d_in[8];
  } else {                    // signature order: x,Wq,Wk,Wv,Wo,bq,bk,bv,bo
    Wq = (const float*)d_in[1]; Wk = (const float*)d_in[2];
    Wv = (const float*)d_in[3]; Wo = (const float*)d_in[4];
    bq = (const float*)d_in[5]; bk = (const float*)d_in[6];
    bv = (const float*)d_in[7]; bo = (const float*)d_in[8];
  }
  const size_t NT = (size_t)4 * 16 * 2048 * 64;  // 8.39M elems per tensor
  const size_t NW = (size_t)1024 * 1024;
  unsigned short* ws = (unsigned short*)d_ws;
  unsigned short* xb = ws;                 // x bf16; reused as attn-out later
  unsigned short* q  = ws + NT;
  unsigned short* k  = ws + 2 * NT;
  unsigned short* vt = ws + 3 * NT;        // V^T [BH, hd, S]
  unsigned short* ao = xb;                 // alias: xb dead after gemm_qkv
  unsigned short* wq = (unsigned short*)d_out;  // d_out dead until gemm_o
  unsigned short* wk = wq + NW;
  unsigned short* wv = wk + NW;
  unsigned short* wo = q;                  // q dead after attn

  convert_f32_bf16<<<(int)(NT / 4 + 255) / 256, 256, 0, stream>>>(x, xb, (int)(NT / 4));
  convert3_f32_bf16<<<dim3((int)(NW / 4 + 255) / 256, 3), 256, 0, stream>>>(
      Wq, Wk, Wv, wq, wk, wv, (int)(NW / 4));

  gemm_qkv<<<dim3(64, 24), 256, 0, stream>>>(xb, wq, wk, wv, bq, bk, bv, q, k, vt);
  attn_kernel<<<dim3(32, 64), 256, 0, stream>>>(q, k, vt, ao);

  convert_f32_bf16<<<(int)(NW / 4 + 255) / 256, 256, 0, stream>>>(Wo, wo, (int)(NW / 4));
  gemm_o<<<dim3(64, 8), 256, 0, stream>>>(ao, wo, bo, (float*)d_out);
}

// Round 8
// 351.705 us; speedup vs baseline: 1.8647x; 1.8647x over previous
//
#include <hip/hip_runtime.h>
#include <stdint.h>

// ---------------------------------------------------------------------------
// MHA forward. Inputs fp32, output fp32. Internal bf16 MFMA.
//   B=4, S=2048, D=1024, H=16, hd=64.
// converts -> gemm_qkv (x@W^T+b; q pre-scaled by 0.125*log2e; v stored as
// V^T [BH,hd,S]) -> flash attn (round-5 two-barrier shape, 128-q-row blocks:
// 2 subtiles/wave sharing K frags + LDS V tile) -> convert Wo -> gemm_o.
// ws (64 MB): xb|ao [0,NT) q [NT,2NT) k [2NT,3NT) vt [3NT,4NT).
// d_out doubles as bf16 scratch for Wq/Wk/Wv before gemm_o overwrites it.
// ---------------------------------------------------------------------------

typedef __attribute__((ext_vector_type(8))) short bfx8;   // 8 bf16 (4 VGPRs)
typedef __attribute__((ext_vector_type(4))) float fx4;    // MFMA C/D

#define MFMA_16x16x32(A, B, C) __builtin_amdgcn_mfma_f32_16x16x32_bf16(A, B, C, 0, 0, 0)

__device__ __forceinline__ unsigned short f2bf(float f) {
  union { float f; uint32_t u; } v; v.f = f;
  uint32_t r = v.u + 0x7fffu + ((v.u >> 16) & 1u);  // RNE
  return (unsigned short)(r >> 16);
}
__device__ __forceinline__ unsigned short f2bf_fast(float f) {  // round-half-up (p>=0)
  union { float f; uint32_t u; } v; v.f = f;
  return (unsigned short)((v.u + 0x8000u) >> 16);
}
__device__ __forceinline__ void async16(unsigned short* l, const unsigned short* g) {
  // global -> LDS direct copy, 16B/lane. Effective LDS dest = wave base + lane*16.
  __builtin_amdgcn_global_load_lds((const __attribute__((address_space(1))) void*)g,
                                   (__attribute__((address_space(3))) void*)l,
                                   16, 0, 0);
}

// ---------------------------------------------------------------------------
// fp32 -> bf16 converts
// ---------------------------------------------------------------------------
__global__ __launch_bounds__(256) void convert_f32_bf16(
    const float* __restrict__ src, unsigned short* __restrict__ dst, int n4) {
  const int i = blockIdx.x * 256 + threadIdx.x;
  if (i >= n4) return;
  const float4 v = ((const float4*)src)[i];
  ushort4 o;
  o.x = f2bf(v.x); o.y = f2bf(v.y); o.z = f2bf(v.z); o.w = f2bf(v.w);
  ((ushort4*)dst)[i] = o;
}

__global__ __launch_bounds__(256) void convert3_f32_bf16(
    const float* __restrict__ s0, const float* __restrict__ s1,
    const float* __restrict__ s2,
    unsigned short* __restrict__ d0, unsigned short* __restrict__ d1,
    unsigned short* __restrict__ d2, int n4) {
  const int which = blockIdx.y;
  const float* src = (which == 0) ? s0 : ((which == 1) ? s1 : s2);
  unsigned short* dst = (which == 0) ? d0 : ((which == 1) ? d1 : d2);
  const int i = blockIdx.x * 256 + threadIdx.x;
  if (i >= n4) return;
  const float4 v = ((const float4*)src)[i];
  ushort4 o;
  o.x = f2bf(v.x); o.y = f2bf(v.y); o.z = f2bf(v.z); o.w = f2bf(v.w);
  ((ushort4*)dst)[i] = o;
}

// ---------------------------------------------------------------------------
// GEMM: Y = X @ W^T + b.  128x128 tile, BK=32, 4 waves 2x2, 4x4 16x16 subtiles.
// which==0 (q): out *= 0.125*log2e. which==2 (v): stores V^T [BH, hd, S].
// ---------------------------------------------------------------------------

__global__ __launch_bounds__(256) void gemm_qkv(
    const unsigned short* __restrict__ X,
    const unsigned short* __restrict__ Wq, const unsigned short* __restrict__ Wk,
    const unsigned short* __restrict__ Wv,
    const float* __restrict__ bq, const float* __restrict__ bk,
    const float* __restrict__ bv,
    unsigned short* __restrict__ outq, unsigned short* __restrict__ outk,
    unsigned short* __restrict__ outv) {
  __shared__ unsigned short ldsA[128 * 32];
  __shared__ unsigned short ldsB[128 * 32];
  const int tid = threadIdx.x;
  const int w = tid >> 6, lane = tid & 63, quad = lane >> 4, l15 = lane & 15;
  const int m0 = blockIdx.x * 128;
  const int which = blockIdx.y >> 3;          // 0:q 1:k 2:v
  const int n0 = (blockIdx.y & 7) * 128;
  const unsigned short* W = (which == 0) ? Wq : ((which == 1) ? Wk : Wv);
  const float* bias       = (which == 0) ? bq : ((which == 1) ? bk : bv);
  unsigned short* Y       = (which == 0) ? outq : ((which == 1) ? outk : outv);
  const int wm = (w >> 1) * 64, wn = (w & 1) * 64;
  const int srow = tid >> 2, scol = (tid & 3) * 8;   // per-lane 16B staging
  fx4 acc[4][4] = {};
  for (int k0 = 0; k0 < 1024; k0 += 32) {
    __syncthreads();
    async16(&ldsA[srow * 32 + scol],        X + (size_t)(m0 + srow) * 1024 + k0 + scol);
    async16(&ldsA[(srow + 64) * 32 + scol], X + (size_t)(m0 + srow + 64) * 1024 + k0 + scol);
    async16(&ldsB[srow * 32 + scol],        W + (size_t)(n0 + srow) * 1024 + k0 + scol);
    async16(&ldsB[(srow + 64) * 32 + scol], W + (size_t)(n0 + srow + 64) * 1024 + k0 + scol);
    __syncthreads();
    bfx8 af[4], bfr[4];
#pragma unroll
    for (int i = 0; i < 4; i++) af[i]  = *(const bfx8*)&ldsA[(wm + i * 16 + l15) * 32 + quad * 8];
#pragma unroll
    for (int j = 0; j < 4; j++) bfr[j] = *(const bfx8*)&ldsB[(wn + j * 16 + l15) * 32 + quad * 8];
#pragma unroll
    for (int i = 0; i < 4; i++)
#pragma unroll
      for (int j = 0; j < 4; j++)
        acc[i][j] = MFMA_16x16x32(af[i], bfr[j], acc[i][j]);
  }
  const float qscale = 0.18033688011112042f;  // 0.125 * log2(e)
  float bv_[4];
#pragma unroll
  for (int j = 0; j < 4; j++) bv_[j] = bias[n0 + wn + j * 16 + l15];
#pragma unroll
  for (int i = 0; i < 4; i++) {
#pragma unroll
    for (int r = 0; r < 4; r++) {
      const int m_g = m0 + wm + i * 16 + quad * 4 + r;     // C/D: row = quad*4+reg
      const int bb = m_g >> 11, ss = m_g & 2047;
#pragma unroll
      for (int j = 0; j < 4; j++) {
        const int n_g = n0 + wn + j * 16 + l15;            // C/D: col = lane&15
        const int h = n_g >> 6, d = n_g & 63;
        float o = acc[i][j][r] + bv_[j];
        if (which == 0) o *= qscale;                       // wave-uniform branch
        if (which == 2)  // V^T: [BH, hd, S]
          Y[((size_t)(bb * 16 + h) * 64 + d) * 2048 + ss] = f2bf(o);
        else
          Y[(((size_t)(bb * 16 + h)) * 2048 + ss) * 64 + d] = f2bf(o);
      }
    }
  }
}

__global__ __launch_bounds__(256) void gemm_o(
    const unsigned short* __restrict__ X,   // attn_out [8192,1024] bf16
    const unsigned short* __restrict__ W,   // Wo bf16
    const float* __restrict__ bias,
    float* __restrict__ Y) {                // d_out [8192,1024] fp32
  __shared__ unsigned short ldsA[128 * 32];
  __shared__ unsigned short ldsB[128 * 32];
  const int tid = threadIdx.x;
  const int w = tid >> 6, lane = tid & 63, quad = lane >> 4, l15 = lane & 15;
  const int m0 = blockIdx.x * 128;
  const int n0 = blockIdx.y * 128;
  const int wm = (w >> 1) * 64, wn = (w & 1) * 64;
  const int srow = tid >> 2, scol = (tid & 3) * 8;
  fx4 acc[4][4] = {};
  for (int k0 = 0; k0 < 1024; k0 += 32) {
    __syncthreads();
    async16(&ldsA[srow * 32 + scol],        X + (size_t)(m0 + srow) * 1024 + k0 + scol);
    async16(&ldsA[(srow + 64) * 32 + scol], X + (size_t)(m0 + srow + 64) * 1024 + k0 + scol);
    async16(&ldsB[srow * 32 + scol],        W + (size_t)(n0 + srow) * 1024 + k0 + scol);
    async16(&ldsB[(srow + 64) * 32 + scol], W + (size_t)(n0 + srow + 64) * 1024 + k0 + scol);
    __syncthreads();
    bfx8 af[4], bfr[4];
#pragma unroll
    for (int i = 0; i < 4; i++) af[i]  = *(const bfx8*)&ldsA[(wm + i * 16 + l15) * 32 + quad * 8];
#pragma unroll
    for (int j = 0; j < 4; j++) bfr[j] = *(const bfx8*)&ldsB[(wn + j * 16 + l15) * 32 + quad * 8];
#pragma unroll
    for (int i = 0; i < 4; i++)
#pragma unroll
      for (int j = 0; j < 4; j++)
        acc[i][j] = MFMA_16x16x32(af[i], bfr[j], acc[i][j]);
  }
  float bv_[4];
#pragma unroll
  for (int j = 0; j < 4; j++) bv_[j] = bias[n0 + wn + j * 16 + l15];
#pragma unroll
  for (int i = 0; i < 4; i++) {
#pragma unroll
    for (int r = 0; r < 4; r++) {
      const int m_g = m0 + wm + i * 16 + quad * 4 + r;
#pragma unroll
      for (int j = 0; j < 4; j++) {
        const int n_g = n0 + wn + j * 16 + l15;
        Y[(size_t)m_g * 1024 + n_g] = acc[i][j][r] + bv_[j];
      }
    }
  }
}

// ---------------------------------------------------------------------------
// Flash attention, fixed-max softmax (q pre-scaled by 0.125*log2e).
// Q,K: [BH,S,64]; VT: [BH,64,S]. Block = (b,h) x 128 q rows; 4 waves, each
// wave owns 2 subtiles of 16 q rows (q0+0, q0+16). kv tiles of 64.
// Round-5 two-barrier shape:
//   barrier A -> async-stage V^T (shared, XOR-swizzled) -> S for both
//   subtiles (K frags loaded once, shared) -> softmax -> P -> barrier B ->
//   PV for both subtiles from shared LDS V.
// K/V traffic and barrier count per FLOP are HALVED vs the 64-row block.
// __launch_bounds__(256,4): cap at 128 VGPR for 16 waves/CU.
// ---------------------------------------------------------------------------

#define P_LD 68

__global__ __launch_bounds__(256, 4) void attn_kernel(
    const unsigned short* __restrict__ Q, const unsigned short* __restrict__ K,
    const unsigned short* __restrict__ VT, unsigned short* __restrict__ O) {
  __shared__ unsigned short lds_vt[64 * 64];        // swizzled V^T tile (8 KB)
  __shared__ unsigned short lds_p[4][32 * P_LD];    // per-wave P, 2 subtiles (17.4 KB)
  const int tid = threadIdx.x;
  const int w = tid >> 6, lane = tid & 63, quad = lane >> 4, l15 = lane & 15;
  const int bh = blockIdx.y;
  const size_t hoff = (size_t)bh * 2048 * 64;
  const unsigned short* Qh = Q + hoff;
  const unsigned short* Kh = K + hoff;
  const unsigned short* VTh = VT + hoff;            // [64][2048]
  const int q0 = blockIdx.x * 128 + w * 32;         // wave owns rows q0..q0+31

  // Q fragments for 2 subtiles (A-layout: m=lane&15, k=quad*8+j), pre-scaled
  bfx8 qf[2][2];
#pragma unroll
  for (int s = 0; s < 2; s++) {
    qf[s][0] = *(const bfx8*)&Qh[(size_t)(q0 + s * 16 + l15) * 64 + quad * 8];
    qf[s][1] = *(const bfx8*)&Qh[(size_t)(q0 + s * 16 + l15) * 64 + 32 + quad * 8];
  }

  fx4 o_acc[2][4] = {};
  float l_r[2][4] = {};

  // V^T staging (as round 5): row off lane>>3, seg lane&7; XOR seg swizzle.
  const int vr0 = w * 8 + (lane >> 3);
  const int vr1 = vr0 + 32;
  const int seg = lane & 7;
  const unsigned short* vsrc0 = VTh + (size_t)vr0 * 2048 + ((seg ^ (vr0 & 7)) * 8);
  const unsigned short* vsrc1 = VTh + (size_t)vr1 * 2048 + ((seg ^ (vr1 & 7)) * 8);
  unsigned short* vdst0 = &lds_vt[vr0 * 64 + seg * 8];
  unsigned short* vdst1 = &lds_vt[vr1 * 64 + seg * 8];

  // swizzled read segs for PV B-frags (row = nj*16+l15 -> row&7 = l15&7)
  const int s0v = (quad ^ (l15 & 7)) * 8;
  const int s1v = ((quad + 4) ^ (l15 & 7)) * 8;

  for (int t = 0; t < 32; ++t) {
    const int kv0 = t * 64;
    __syncthreads();                 // A: prev tile's lds_vt/lds_p reads done
    async16(vdst0, vsrc0 + kv0);
    async16(vdst1, vsrc1 + kv0);

    // S for both subtiles; K frags loaded once per nj (transient regs)
    fx4 s0a[4], s1a[4];
#pragma unroll
    for (int nj = 0; nj < 4; nj++) {
      const size_t krow = (size_t)(kv0 + nj * 16 + l15) * 64;
      bfx8 kf0 = *(const bfx8*)&Kh[krow + quad * 8];
      bfx8 kf1 = *(const bfx8*)&Kh[krow + 32 + quad * 8];
      fx4 z0 = {}, z1 = {};
      z0 = MFMA_16x16x32(qf[0][0], kf0, z0);
      z0 = MFMA_16x16x32(qf[0][1], kf1, z0);
      z1 = MFMA_16x16x32(qf[1][0], kf0, z1);
      z1 = MFMA_16x16x32(qf[1][1], kf1, z1);
      s0a[nj] = z0;
      s1a[nj] = z1;
    }

    // fixed-max softmax per subtile: p = exp2(z); l partials; P -> LDS bf16
#pragma unroll
    for (int s = 0; s < 2; s++) {
      const fx4* sa = (s == 0) ? s0a : s1a;
#pragma unroll
      for (int r = 0; r < 4; r++) {
        float p0 = exp2f(sa[0][r]);
        float p1 = exp2f(sa[1][r]);
        float p2 = exp2f(sa[2][r]);
        float p3 = exp2f(sa[3][r]);
        l_r[s][r] += (p0 + p1) + (p2 + p3);
        const int pbase = (s * 16 + quad * 4 + r) * P_LD + l15;
        lds_p[w][pbase]      = f2bf_fast(p0);
        lds_p[w][pbase + 16] = f2bf_fast(p1);
        lds_p[w][pbase + 32] = f2bf_fast(p2);
        lds_p[w][pbase + 48] = f2bf_fast(p3);
      }
    }

    __syncthreads();                 // B: V^T landed; P visible

    // O += P V for both subtiles; V B-frags shared from swizzled LDS
    bfx8 pf[2][2];
#pragma unroll
    for (int s = 0; s < 2; s++) {
      pf[s][0] = *(const bfx8*)&lds_p[w][(s * 16 + l15) * P_LD + quad * 8];
      pf[s][1] = *(const bfx8*)&lds_p[w][(s * 16 + l15) * P_LD + 32 + quad * 8];
    }
#pragma unroll
    for (int nj = 0; nj < 4; nj++) {
      const int vrow = (nj * 16 + l15) * 64;
      bfx8 vf0 = *(const bfx8*)&lds_vt[vrow + s0v];
      bfx8 vf1 = *(const bfx8*)&lds_vt[vrow + s1v];
      o_acc[0][nj] = MFMA_16x16x32(pf[0][0], vf0, o_acc[0][nj]);
      o_acc[0][nj] = MFMA_16x16x32(pf[0][1], vf1, o_acc[0][nj]);
      o_acc[1][nj] = MFMA_16x16x32(pf[1][0], vf0, o_acc[1][nj]);
      o_acc[1][nj] = MFMA_16x16x32(pf[1][1], vf1, o_acc[1][nj]);
    }
  }

  // epilogue: reduce l across 16 lanes per row, O /= l, store bf16 [B,S,D]
  const int bb = bh >> 4, h = bh & 15;
#pragma unroll
  for (int s = 0; s < 2; s++) {
#pragma unroll
    for (int r = 0; r < 4; r++) {
      float sum = l_r[s][r];
#pragma unroll
      for (int d = 1; d < 16; d <<= 1) sum += __shfl_xor(sum, d, 64);
      const float inv = 1.0f / sum;
      const int qrow = q0 + s * 16 + quad * 4 + r;
      const size_t base = ((size_t)(bb * 2048 + qrow)) * 1024 + h * 64;
#pragma unroll
      for (int nj = 0; nj < 4; nj++)
        O[base + nj * 16 + l15] = f2bf(o_acc[s][nj][r] * inv);
    }
  }
}

// ---------------------------------------------------------------------------

extern "C" void kernel_launch(void* const* d_in, const int* in_sizes, int n_in,
                              void* d_out, int out_size, void* d_ws, size_t ws_size,
                              hipStream_t stream) {
  const float* x = (const float*)d_in[0];
  const float *Wq, *Wk, *Wv, *Wo, *bq, *bk, *bv, *bo;
  if (in_sizes[2] == 1024) {  // setup_inputs() dict order: x,Wq,bq,Wk,bk,Wv,bv,Wo,bo
    Wq = (const float*)d_in[1]; bq = (const float*)d_in[2];
    Wk = (const float*)d_in[3]; bk = (const float*)d_in[4];
    Wv = (const float*)d_in[5]; bv = (const float*)d_in[6];
    Wo = (const float*)d_in[7]; bo = (const float*)d_in[8];
  } else {                    // signature order: x,Wq,Wk,Wv,Wo,bq,bk,bv,bo
    Wq = (const float*)d_in[1]; Wk = (const float*)d_in[2];
    Wv = (const float*)d_in[3]; Wo = (const float*)d_in[4];
    bq = (const float*)d_in[5]; bk = (const float*)d_in[6];
    bv = (const float*)d_in[7]; bo = (const float*)d_in[8];
  }
  const size_t NT = (size_t)4 * 16 * 2048 * 64;  // 8.39M elems per tensor
  const size_t NW = (size_t)1024 * 1024;
  unsigned short* ws = (unsigned short*)d_ws;
  unsigned short* xb = ws;                 // x bf16; reused as attn-out later
  unsigned short* q  = ws + NT;
  unsigned short* k  = ws + 2 * NT;
  unsigned short* vt = ws + 3 * NT;        // V^T [BH, hd, S]
  unsigned short* ao = xb;                 // alias: xb dead after gemm_qkv
  unsigned short* wq = (unsigned short*)d_out;  // d_out dead until gemm_o
  unsigned short* wk = wq + NW;
  unsigned short* wv = wk + NW;
  unsigned short* wo = q;                  // q dead after attn

  convert_f32_bf16<<<(int)(NT / 4 + 255) / 256, 256, 0, stream>>>(x, xb, (int)(NT / 4));
  convert3_f32_bf16<<<dim3((int)(NW / 4 + 255) / 256, 3), 256, 0, stream>>>(
      Wq, Wk, Wv, wq, wk, wv, (int)(NW / 4));

  gemm_qkv<<<dim3(64, 24), 256, 0, stream>>>(xb, wq, wk, wv, bq, bk, bv, q, k, vt);
  attn_kernel<<<dim3(16, 64), 256, 0, stream>>>(q, k, vt, ao);

  convert_f32_bf16<<<(int)(NW / 4 + 255) / 256, 256, 0, stream>>>(Wo, wo, (int)(NW / 4));
  gemm_o<<<dim3(64, 8), 256, 0, stream>>>(ao, wo, bo, (float*)d_out);
}